// Round 2
// baseline (2198.382 us; speedup 1.0000x reference)
//
#include <hip/hip_runtime.h>
#include <hip/hip_bf16.h>
#include <stdint.h>

#define NUM_FF 7
#define DM 512
#define CARRY 384
#define RD 128
#define VOCABN 128
#define BATCH 128
#define TLEN 1024

// ---- pack ff: ffp[l][k][j] bit i = (ff[l][32k+i][j] > 0) ----
__global__ void pack_ff_kernel(const float* __restrict__ ff, uint32_t* __restrict__ ffp) {
    int idx = blockIdx.x * blockDim.x + threadIdx.x;
    if (idx >= NUM_FF * 16 * DM) return;
    int j = idx & (DM - 1);
    int k = (idx >> 9) & 15;
    int l = idx >> 13;
    const float* base = ff + (size_t)l * DM * DM + (size_t)(k * 32) * DM + j;
    uint32_t w = 0;
#pragma unroll
    for (int i = 0; i < 32; ++i)
        w |= (base[(size_t)i * DM] > 0.0f ? 1u : 0u) << i;
    ffp[idx] = w;
}

// ---- pack embed/head/initial (512 threads, 1 block) ----
__global__ void pack_small_kernel(const float* __restrict__ embed,
                                  const float* __restrict__ head,
                                  const float* __restrict__ initial,
                                  uint32_t* __restrict__ embp,
                                  uint32_t* __restrict__ headp,
                                  uint32_t* __restrict__ initp) {
    int idx = threadIdx.x; // 512
    {   // embp[v*4+k] bit i = embed[v][32k+i] > 0
        int v = idx >> 2, k = idx & 3;
        uint32_t w = 0;
#pragma unroll
        for (int i = 0; i < 32; ++i)
            w |= (embed[v * RD + k * 32 + i] > 0.0f ? 1u : 0u) << i;
        embp[idx] = w;
    }
    {   // headp[k*128+v] bit i = head[32k+i][v] > 0
        int k = idx >> 7, v = idx & 127;
        uint32_t w = 0;
#pragma unroll
        for (int i = 0; i < 32; ++i)
            w |= (head[(k * 32 + i) * VOCABN + v] > 0.0f ? 1u : 0u) << i;
        headp[idx] = w;
    }
    if (idx < 16) {
        uint32_t w = 0;
#pragma unroll
        for (int i = 0; i < 32; ++i)
            w |= (initial[idx * 32 + i] > 0.0f ? 1u : 0u) << i;
        initp[idx] = w;
    }
}

__device__ __forceinline__ int bdot16(uint4 s0, uint4 s1, uint4 s2, uint4 s3,
                                      const uint32_t* __restrict__ w) {
    // two serial accumulate chains -> v_bcnt_u32_b32 fusion, 2-way ILP
    int a = __popc(s0.x ^ w[0]);
    a += __popc(s0.y ^ w[1]);
    a += __popc(s0.z ^ w[2]);
    a += __popc(s0.w ^ w[3]);
    a += __popc(s1.x ^ w[4]);
    a += __popc(s1.y ^ w[5]);
    a += __popc(s1.z ^ w[6]);
    a += __popc(s1.w ^ w[7]);
    int b = __popc(s2.x ^ w[8]);
    b += __popc(s2.y ^ w[9]);
    b += __popc(s2.z ^ w[10]);
    b += __popc(s2.w ^ w[11]);
    b += __popc(s3.x ^ w[12]);
    b += __popc(s3.y ^ w[13]);
    b += __popc(s3.z ^ w[14]);
    b += __popc(s3.w ^ w[15]);
    return a + b;
}

// LDS-write visibility + barrier, WITHOUT draining vmcnt (global logit stores
// stay in flight across layers).
#define SYNCB asm volatile("s_waitcnt lgkmcnt(0)\n\ts_barrier" ::: "memory")

// ---- main persistent RNN kernel: 1 workgroup (256 thr, 4 waves) per chain ----
__launch_bounds__(256, 1)
__global__ void brnn_kernel(const int* __restrict__ tokens,
                            const float* __restrict__ ff_thresh,
                            const uint32_t* __restrict__ ffp,
                            const uint32_t* __restrict__ embp,
                            const uint32_t* __restrict__ headp,
                            const uint32_t* __restrict__ initp,
                            float* __restrict__ out) {
    const int b = blockIdx.x;
    const int tid = threadIdx.x;
    const int wv = tid >> 6;
    const int lane = tid & 63;
    const int c0 = (wv << 7) | lane;   // column for ballot 0: 128*wv + lane
    const int c1 = c0 + 64;            // column for ballot 1

    __shared__ uint4 xq0[4], xq1[4];   // double-buffered 512-bit state
    __shared__ uint4 hxv;              // final read-slice words for head
    __shared__ uint32_t emb_lds[VOCABN * 4];
    __shared__ int tok_lds[TLEN + 4];

    // per-thread weights: 2 columns x 7 layers x 16 words = 224 VGPRs
    uint32_t wA[NUM_FF][16], wB[NUM_FF][16];
#pragma unroll
    for (int l = 0; l < NUM_FF; ++l)
#pragma unroll
        for (int k = 0; k < 16; ++k) {
            wA[l][k] = ffp[l * (16 * DM) + k * DM + c0];
            wB[l][k] = ffp[l * (16 * DM) + k * DM + c1];
        }
    float thA[NUM_FF], thB[NUM_FF];
#pragma unroll
    for (int l = 0; l < NUM_FF; ++l) {
        thA[l] = ff_thresh[l * DM + c0];
        thB[l] = ff_thresh[l * DM + c1];
    }
    uint32_t h0 = 0, h1 = 0, h2 = 0, h3 = 0;
    if (tid < VOCABN) {
        h0 = headp[0 * VOCABN + tid];
        h1 = headp[1 * VOCABN + tid];
        h2 = headp[2 * VOCABN + tid];
        h3 = headp[3 * VOCABN + tid];
    }
    emb_lds[tid] = embp[tid];
    emb_lds[tid + 256] = embp[tid + 256];
    tok_lds[tid] = tokens[b * TLEN + tid];
    tok_lds[tid + 256] = tokens[b * TLEN + tid + 256];
    tok_lds[tid + 512] = tokens[b * TLEN + tid + 512];
    tok_lds[tid + 768] = tokens[b * TLEN + tid + 768];
    if (tid == 0) tok_lds[TLEN] = 0;  // dummy for last step's prefetch
    if (tid < 16) ((uint32_t*)xq0)[tid] = initp[tid];
    __syncthreads();
    if (tid < 4) ((uint32_t*)xq0)[12 + tid] = emb_lds[tok_lds[0] * 4 + tid];
    __syncthreads();

    float* outb = out + (size_t)b * TLEN * VOCABN;

#define LAYER(l, SRCQ, DSTQ) do {                                              \
        uint4 s0 = (SRCQ)[0], s1 = (SRCQ)[1], s2 = (SRCQ)[2], s3 = (SRCQ)[3]; \
        int accA = bdot16(s0, s1, s2, s3, wA[l]);                              \
        int accB = bdot16(s0, s1, s2, s3, wB[l]);                              \
        unsigned long long m0 = __ballot((float)(DM - 2 * accA) >= thA[l]);    \
        unsigned long long m1 = __ballot((float)(DM - 2 * accB) >= thB[l]);    \
        if (lane == 0)                                                         \
            (DSTQ)[wv] = make_uint4((uint32_t)m0, (uint32_t)(m0 >> 32),        \
                                    (uint32_t)m1, (uint32_t)(m1 >> 32));       \
        SYNCB;                                                                 \
    } while (0)

#define LAYERF(l, SRCQ, DSTQ, tnext) do {                                      \
        uint4 s0 = (SRCQ)[0], s1 = (SRCQ)[1], s2 = (SRCQ)[2], s3 = (SRCQ)[3]; \
        int accA = bdot16(s0, s1, s2, s3, wA[l]);                              \
        int accB = bdot16(s0, s1, s2, s3, wB[l]);                              \
        unsigned long long m0 = __ballot((float)(DM - 2 * accA) >= thA[l]);    \
        unsigned long long m1 = __ballot((float)(DM - 2 * accB) >= thB[l]);    \
        if (lane == 0) {                                                       \
            uint4 v = make_uint4((uint32_t)m0, (uint32_t)(m0 >> 32),           \
                                 (uint32_t)m1, (uint32_t)(m1 >> 32));          \
            if (wv < 3) (DSTQ)[wv] = v;                                        \
            else hxv = v;                                                      \
        }                                                                      \
        if (tid < 4)                                                           \
            ((uint32_t*)(DSTQ))[12 + tid] = emb_lds[tok_lds[tnext] * 4 + tid]; \
        SYNCB;                                                                 \
    } while (0)

#define HEADOUT(t) do {                                                        \
        if (tid < VOCABN) {                                                    \
            uint4 hv = hxv;                                                    \
            int hc = __popc(hv.x ^ h0) + __popc(hv.y ^ h1) +                   \
                     __popc(hv.z ^ h2) + __popc(hv.w ^ h3);                    \
            outb[(t) * VOCABN + tid] = (float)(RD - 2 * hc);                   \
        }                                                                      \
    } while (0)

    for (int t = 0; t < TLEN; t += 2) {
        // step t (state in xq0)
        LAYER(0, xq0, xq1);
        LAYER(1, xq1, xq0);
        LAYER(2, xq0, xq1);
        LAYER(3, xq1, xq0);
        LAYER(4, xq0, xq1);
        LAYER(5, xq1, xq0);
        LAYERF(6, xq0, xq1, t + 1);
        HEADOUT(t);
        // step t+1 (state in xq1)
        LAYER(0, xq1, xq0);
        LAYER(1, xq0, xq1);
        LAYER(2, xq1, xq0);
        LAYER(3, xq0, xq1);
        LAYER(4, xq1, xq0);
        LAYER(5, xq0, xq1);
        LAYERF(6, xq1, xq0, t + 2);
        HEADOUT(t + 1);
    }
#undef LAYER
#undef LAYERF
#undef HEADOUT
}

extern "C" void kernel_launch(void* const* d_in, const int* in_sizes, int n_in,
                              void* d_out, int out_size, void* d_ws, size_t ws_size,
                              hipStream_t stream) {
    const int* tokens = (const int*)d_in[0];
    const float* initial = (const float*)d_in[1];
    const float* embed = (const float*)d_in[2];
    const float* ff = (const float*)d_in[3];
    const float* ff_thresh = (const float*)d_in[4];
    const float* head = (const float*)d_in[5];
    float* out = (float*)d_out;

    uint32_t* ffp = (uint32_t*)d_ws;              // 7*16*512 = 57344 words
    uint32_t* embp = ffp + NUM_FF * 16 * DM;      // 512 words
    uint32_t* headp = embp + 512;                 // 512 words
    uint32_t* initp = headp + 512;                // 16 words

    pack_ff_kernel<<<(NUM_FF * 16 * DM + 255) / 256, 256, 0, stream>>>(ff, ffp);
    pack_small_kernel<<<1, 512, 0, stream>>>(embed, head, initial, embp, headp, initp);
    brnn_kernel<<<BATCH, 256, 0, stream>>>(tokens, ff_thresh, ffp, embp, headp, initp, out);
}

// Round 3
// 1950.899 us; speedup vs baseline: 1.1269x; 1.1269x over previous
//
#include <hip/hip_runtime.h>
#include <hip/hip_bf16.h>
#include <stdint.h>
#include <math.h>

#define NUM_FF 7
#define DM 512
#define RD 128
#define VOCABN 128
#define BATCH 128
#define TLEN 1024

typedef unsigned int u32x16 __attribute__((ext_vector_type(16)));

// ---- pack ff: ffp[l][k][j] bit i = (ff[l][32k+i][j] > 0) ----
__global__ void pack_ff_kernel(const float* __restrict__ ff, uint32_t* __restrict__ ffp) {
    int idx = blockIdx.x * blockDim.x + threadIdx.x;
    if (idx >= NUM_FF * 16 * DM) return;
    int j = idx & (DM - 1);
    int k = (idx >> 9) & 15;
    int l = idx >> 13;
    const float* base = ff + (size_t)l * DM * DM + (size_t)(k * 32) * DM + j;
    uint32_t w = 0;
#pragma unroll
    for (int i = 0; i < 32; ++i)
        w |= (base[(size_t)i * DM] > 0.0f ? 1u : 0u) << i;
    ffp[idx] = w;
}

// ---- integer thresholds: bit = (512-2a >= th)  <=>  a <= floor((512-th)/2) ----
__global__ void pack_thresh_kernel(const float* __restrict__ th, int* __restrict__ it) {
    int idx = blockIdx.x * blockDim.x + threadIdx.x;
    if (idx < NUM_FF * DM)
        it[idx] = (int)floor((512.0 - (double)th[idx]) * 0.5);
}

// ---- pack embed/head/initial (512 threads, 1 block) ----
__global__ void pack_small_kernel(const float* __restrict__ embed,
                                  const float* __restrict__ head,
                                  const float* __restrict__ initial,
                                  uint32_t* __restrict__ embp,
                                  uint32_t* __restrict__ headp,
                                  uint32_t* __restrict__ initp) {
    int idx = threadIdx.x; // 512
    {   // embp[v*4+k] bit i = embed[v][32k+i] > 0
        int v = idx >> 2, k = idx & 3;
        uint32_t w = 0;
#pragma unroll
        for (int i = 0; i < 32; ++i)
            w |= (embed[v * RD + k * 32 + i] > 0.0f ? 1u : 0u) << i;
        embp[idx] = w;
    }
    {   // headp[k*128+v] bit i = head[32k+i][v] > 0
        int k = idx >> 7, v = idx & 127;
        uint32_t w = 0;
#pragma unroll
        for (int i = 0; i < 32; ++i)
            w |= (head[(k * 32 + i) * VOCABN + v] > 0.0f ? 1u : 0u) << i;
        headp[idx] = w;
    }
    if (idx < 16) {
        uint32_t w = 0;
#pragma unroll
        for (int i = 0; i < 32; ++i)
            w |= (initial[idx * 32 + i] > 0.0f ? 1u : 0u) << i;
        initp[idx] = w;
    }
}

__device__ __forceinline__ int bdot(uint4 s0, uint4 s1, uint4 s2, uint4 s3, u32x16 w) {
    int a = __popc(s0.x ^ w[0]);
    a += __popc(s0.y ^ w[1]);
    a += __popc(s0.z ^ w[2]);
    a += __popc(s0.w ^ w[3]);
    a += __popc(s1.x ^ w[4]);
    a += __popc(s1.y ^ w[5]);
    a += __popc(s1.z ^ w[6]);
    a += __popc(s1.w ^ w[7]);
    int c = __popc(s2.x ^ w[8]);
    c += __popc(s2.y ^ w[9]);
    c += __popc(s2.z ^ w[10]);
    c += __popc(s2.w ^ w[11]);
    c += __popc(s3.x ^ w[12]);
    c += __popc(s3.y ^ w[13]);
    c += __popc(s3.z ^ w[14]);
    c += __popc(s3.w ^ w[15]);
    return a + c;
}

// LDS-visibility barrier WITHOUT draining vmcnt (global logit stores stay in flight)
#define SYNCB asm volatile("s_waitcnt lgkmcnt(0)\n\ts_barrier" ::: "memory")

// ---- main persistent RNN kernel: 1 workgroup (512 thr, 8 waves) per chain ----
__launch_bounds__(512, 2)
__global__ void brnn_kernel(const int* __restrict__ tokens,
                            const uint32_t* __restrict__ ffp,
                            const int* __restrict__ ithr,
                            const uint32_t* __restrict__ embp,
                            const uint32_t* __restrict__ headp,
                            const uint32_t* __restrict__ initp,
                            float* __restrict__ out) {
    const int b = blockIdx.x;
    const int tid = threadIdx.x;      // == output column for this thread
    const int wv = tid >> 6;
    const int lane = tid & 63;

    __shared__ uint4 xq0[4], xq1[4];  // double-buffered 512-bit state
    __shared__ uint4 hx4;             // layer-6 read-slice words for head
    __shared__ uint32_t emb_lds[DM];  // 128 vocab x 4 words
    __shared__ int tok_lds[TLEN + 2];

    // per-thread weights: column `tid`, 7 layers x 16 words, in NAMED vector
    // registers (ext_vector vars are SSA values -> never demoted to scratch)
    u32x16 W0, W1, W2, W3, W4, W5, W6;
#define LOADW(L) { u32x16 w_;                                                  \
        _Pragma("unroll")                                                      \
        for (int k = 0; k < 16; ++k) w_[k] = ffp[(L) * (16 * DM) + k * DM + tid]; \
        W##L = w_; }
    LOADW(0) LOADW(1) LOADW(2) LOADW(3) LOADW(4) LOADW(5) LOADW(6)
#undef LOADW
    const int it0 = ithr[0 * DM + tid];
    const int it1 = ithr[1 * DM + tid];
    const int it2 = ithr[2 * DM + tid];
    const int it3 = ithr[3 * DM + tid];
    const int it4 = ithr[4 * DM + tid];
    const int it5 = ithr[5 * DM + tid];
    const int it6 = ithr[6 * DM + tid];

    // head weights: vocab v = 16*wv + (lane&15), used by lanes 0..15 of each wave
    const int hvv = (wv << 4) | (lane & 15);
    const uint32_t h0 = headp[0 * VOCABN + hvv];
    const uint32_t h1 = headp[1 * VOCABN + hvv];
    const uint32_t h2 = headp[2 * VOCABN + hvv];
    const uint32_t h3 = headp[3 * VOCABN + hvv];

    emb_lds[tid] = embp[tid];
    tok_lds[tid] = tokens[b * TLEN + tid];
    tok_lds[tid + 512] = tokens[b * TLEN + tid + 512];
    if (tid == 0) { tok_lds[TLEN] = 0; tok_lds[TLEN + 1] = 0; }
    if (tid < 16) ((uint32_t*)xq0)[tid] = initp[tid];
    __syncthreads();
    if (tid < 4) ((uint32_t*)xq0)[12 + tid] = emb_lds[tok_lds[0] * 4 + tid];
    __syncthreads();

    float* outb = out + (size_t)b * TLEN * VOCABN;

#define LAYER(L, SRCQ, DSTQ) do {                                              \
        const uint4* xb_ = (const uint4*)(SRCQ);                               \
        uint4 s0 = xb_[0], s1 = xb_[1], s2 = xb_[2], s3 = xb_[3];              \
        int acc = bdot(s0, s1, s2, s3, W##L);                                  \
        unsigned long long m = __ballot(acc <= it##L);                         \
        if (lane == 0)                                                         \
            ((uint2*)(DSTQ))[wv] = make_uint2((uint32_t)m, (uint32_t)(m >> 32)); \
        SYNCB;                                                                 \
    } while (0)

#define LAYERF(SRCQ, DSTQ) do {                                                \
        const uint4* xb_ = (const uint4*)(SRCQ);                               \
        uint4 s0 = xb_[0], s1 = xb_[1], s2 = xb_[2], s3 = xb_[3];              \
        int acc = bdot(s0, s1, s2, s3, W6);                                    \
        unsigned long long m = __ballot(acc <= it6);                           \
        if (lane == 0) {                                                       \
            uint2 v_ = make_uint2((uint32_t)m, (uint32_t)(m >> 32));           \
            if (wv < 6) ((uint2*)(DSTQ))[wv] = v_;                             \
            else ((uint2*)&hx4)[wv - 6] = v_;                                  \
        }                                                                      \
        if (wv == 7 && lane < 4) ((uint32_t*)(DSTQ))[12 + lane] = embw;        \
        SYNCB;                                                                 \
    } while (0)

#define STEP(AQ, BQ, T) do {                                                   \
        /* prefetch next token's embedding early (wave 7 only) */              \
        uint32_t embw = 0;                                                     \
        if (wv == 7) embw = emb_lds[tok_lds[(T) + 1] * 4 + (lane & 3)];        \
        LAYER(0, AQ, BQ);                                                      \
        LAYER(1, BQ, AQ);                                                      \
        LAYER(2, AQ, BQ);                                                      \
        LAYER(3, BQ, AQ);                                                      \
        LAYER(4, AQ, BQ);                                                      \
        LAYER(5, BQ, AQ);                                                      \
        LAYERF(AQ, BQ);                                                        \
        uint4 hv_ = hx4;                                                       \
        if (lane < 16) {                                                       \
            int hc = __popc(hv_.x ^ h0) + __popc(hv_.y ^ h1) +                 \
                     __popc(hv_.z ^ h2) + __popc(hv_.w ^ h3);                  \
            outb[(T) * VOCABN + hvv] = (float)(RD - 2 * hc);                   \
        }                                                                      \
    } while (0)

    for (int t = 0; t < TLEN; t += 2) {
        STEP(xq0, xq1, t);
        STEP(xq1, xq0, t + 1);
    }
#undef LAYER
#undef LAYERF
#undef STEP
}

extern "C" void kernel_launch(void* const* d_in, const int* in_sizes, int n_in,
                              void* d_out, int out_size, void* d_ws, size_t ws_size,
                              hipStream_t stream) {
    const int* tokens = (const int*)d_in[0];
    const float* initial = (const float*)d_in[1];
    const float* embed = (const float*)d_in[2];
    const float* ff = (const float*)d_in[3];
    const float* ff_thresh = (const float*)d_in[4];
    const float* head = (const float*)d_in[5];
    float* out = (float*)d_out;

    uint32_t* ffp = (uint32_t*)d_ws;              // 7*16*512 = 57344 words
    uint32_t* embp = ffp + NUM_FF * 16 * DM;      // 512 words
    uint32_t* headp = embp + 512;                 // 512 words
    uint32_t* initp = headp + 512;                // 16 words
    int* ithr = (int*)(initp + 16);               // 7*512 ints

    pack_ff_kernel<<<(NUM_FF * 16 * DM + 255) / 256, 256, 0, stream>>>(ff, ffp);
    pack_thresh_kernel<<<(NUM_FF * DM + 255) / 256, 256, 0, stream>>>(ff_thresh, ithr);
    pack_small_kernel<<<1, 512, 0, stream>>>(embed, head, initial, embp, headp, initp);
    brnn_kernel<<<BATCH, 512, 0, stream>>>(tokens, ffp, ithr, embp, headp, initp, out);
}

// Round 4
// 1945.823 us; speedup vs baseline: 1.1298x; 1.0026x over previous
//
#include <hip/hip_runtime.h>
#include <hip/hip_bf16.h>
#include <stdint.h>
#include <math.h>

#define NUM_FF 7
#define DM 512
#define RD 128
#define VOCABN 128
#define BATCH 128
#define TLEN 1024

typedef unsigned int u32x4 __attribute__((ext_vector_type(4)));

// ---- pack ff: ffp[l][k][j] bit i = (ff[l][32k+i][j] > 0) ----
__global__ void pack_ff_kernel(const float* __restrict__ ff, uint32_t* __restrict__ ffp) {
    int idx = blockIdx.x * blockDim.x + threadIdx.x;
    if (idx >= NUM_FF * 16 * DM) return;
    int j = idx & (DM - 1);
    int k = (idx >> 9) & 15;
    int l = idx >> 13;
    const float* base = ff + (size_t)l * DM * DM + (size_t)(k * 32) * DM + j;
    uint32_t w = 0;
#pragma unroll
    for (int i = 0; i < 32; ++i)
        w |= (base[(size_t)i * DM] > 0.0f ? 1u : 0u) << i;
    ffp[idx] = w;
}

// ---- integer thresholds: bit = (512-2a >= th)  <=>  a <= floor((512-th)/2) ----
__global__ void pack_thresh_kernel(const float* __restrict__ th, int* __restrict__ it) {
    int idx = blockIdx.x * blockDim.x + threadIdx.x;
    if (idx < NUM_FF * DM)
        it[idx] = (int)floor((512.0 - (double)th[idx]) * 0.5);
}

// ---- pack embed/head/initial (512 threads, 1 block) ----
__global__ void pack_small_kernel(const float* __restrict__ embed,
                                  const float* __restrict__ head,
                                  const float* __restrict__ initial,
                                  uint32_t* __restrict__ embp,
                                  uint32_t* __restrict__ headp,
                                  uint32_t* __restrict__ initp) {
    int idx = threadIdx.x; // 512
    {   // embp[v*4+k] bit i = embed[v][32k+i] > 0
        int v = idx >> 2, k = idx & 3;
        uint32_t w = 0;
#pragma unroll
        for (int i = 0; i < 32; ++i)
            w |= (embed[v * RD + k * 32 + i] > 0.0f ? 1u : 0u) << i;
        embp[idx] = w;
    }
    {   // headp[k*128+v] bit i = head[32k+i][v] > 0
        int k = idx >> 7, v = idx & 127;
        uint32_t w = 0;
#pragma unroll
        for (int i = 0; i < 32; ++i)
            w |= (head[(k * 32 + i) * VOCABN + v] > 0.0f ? 1u : 0u) << i;
        headp[idx] = w;
    }
    if (idx < 16) {
        uint32_t w = 0;
#pragma unroll
        for (int i = 0; i < 32; ++i)
            w |= (initial[idx * 32 + i] > 0.0f ? 1u : 0u) << i;
        initp[idx] = w;
    }
}

__device__ __forceinline__ int bdot4(uint4 s0, uint4 s1, uint4 s2, uint4 s3,
                                     u32x4 w0, u32x4 w1, u32x4 w2, u32x4 w3) {
    int a = __popc(s0.x ^ w0[0]);
    a += __popc(s0.y ^ w0[1]);
    a += __popc(s0.z ^ w0[2]);
    a += __popc(s0.w ^ w0[3]);
    a += __popc(s1.x ^ w1[0]);
    a += __popc(s1.y ^ w1[1]);
    a += __popc(s1.z ^ w1[2]);
    a += __popc(s1.w ^ w1[3]);
    int c = __popc(s2.x ^ w2[0]);
    c += __popc(s2.y ^ w2[1]);
    c += __popc(s2.z ^ w2[2]);
    c += __popc(s2.w ^ w2[3]);
    c += __popc(s3.x ^ w3[0]);
    c += __popc(s3.y ^ w3[1]);
    c += __popc(s3.z ^ w3[2]);
    c += __popc(s3.w ^ w3[3]);
    return a + c;
}

// LDS-visibility barrier WITHOUT draining vmcnt (global logit stores stay in flight)
#define SYNCB asm volatile("s_waitcnt lgkmcnt(0)\n\ts_barrier" ::: "memory")

// ---- main persistent RNN kernel: 1 workgroup (512 thr, 8 waves) per chain ----
__launch_bounds__(512, 2)
__global__ void brnn_kernel(const int* __restrict__ tokens,
                            const uint32_t* __restrict__ ffp,
                            const int* __restrict__ ithr,
                            const uint32_t* __restrict__ embp,
                            const uint32_t* __restrict__ headp,
                            const uint32_t* __restrict__ initp,
                            float* __restrict__ out) {
    const int b = blockIdx.x;
    const int tid = threadIdx.x;      // == output column for this thread
    const int wv = tid >> 6;
    const int lane = tid & 63;

    __shared__ uint4 xq0[4], xq1[4];  // double-buffered 512-bit state
    __shared__ uint4 hx4;             // layer-6 read-slice words for head
    __shared__ uint32_t emb_lds[DM];  // 128 vocab x 4 words
    __shared__ int tok_lds[TLEN + 2];

    // per-thread weights: column `tid`, 7 layers x 4 u32x4 chunks. After the
    // KEEP asm, each chunk is an opaque asm result: the compiler CANNOT
    // rematerialize the global loads inside the t-loop (the round-1..3 bug:
    // VGPR_Count 76-144 with 1.3 GB/dispatch FETCH_SIZE of weight re-reads).
    u32x4 w[NUM_FF][4];
#pragma unroll
    for (int l = 0; l < NUM_FF; ++l)
#pragma unroll
        for (int q = 0; q < 4; ++q) {
            u32x4 t_;
#pragma unroll
            for (int k = 0; k < 4; ++k)
                t_[k] = ffp[l * (16 * DM) + (q * 4 + k) * DM + tid];
            w[l][q] = t_;
        }
#define KEEP(L) asm volatile("" : "+v"(w[L][0]), "+v"(w[L][1]), "+v"(w[L][2]), "+v"(w[L][3]))
    KEEP(0); KEEP(1); KEEP(2); KEEP(3); KEEP(4); KEEP(5); KEEP(6);
#undef KEEP

    const int it0 = ithr[0 * DM + tid];
    const int it1 = ithr[1 * DM + tid];
    const int it2 = ithr[2 * DM + tid];
    const int it3 = ithr[3 * DM + tid];
    const int it4 = ithr[4 * DM + tid];
    const int it5 = ithr[5 * DM + tid];
    const int it6 = ithr[6 * DM + tid];

    // head weights: vocab v = 16*wv + (lane&15), used by lanes 0..15 of each wave
    const int hvv = (wv << 4) | (lane & 15);
    const uint32_t h0 = headp[0 * VOCABN + hvv];
    const uint32_t h1 = headp[1 * VOCABN + hvv];
    const uint32_t h2 = headp[2 * VOCABN + hvv];
    const uint32_t h3 = headp[3 * VOCABN + hvv];

    emb_lds[tid] = embp[tid];
    tok_lds[tid] = tokens[b * TLEN + tid];
    tok_lds[tid + 512] = tokens[b * TLEN + tid + 512];
    if (tid == 0) { tok_lds[TLEN] = 0; tok_lds[TLEN + 1] = 0; }
    if (tid < 16) ((uint32_t*)xq0)[tid] = initp[tid];
    __syncthreads();
    if (tid < 4) ((uint32_t*)xq0)[12 + tid] = emb_lds[tok_lds[0] * 4 + tid];
    __syncthreads();

    float* outb = out + (size_t)b * TLEN * VOCABN;

#define LAYER(L, SRCQ, DSTQ) do {                                              \
        const uint4* xb_ = (const uint4*)(SRCQ);                               \
        uint4 s0 = xb_[0], s1 = xb_[1], s2 = xb_[2], s3 = xb_[3];              \
        int acc = bdot4(s0, s1, s2, s3, w[L][0], w[L][1], w[L][2], w[L][3]);   \
        unsigned long long m = __ballot(acc <= it##L);                         \
        if (lane == 0)                                                         \
            ((uint2*)(DSTQ))[wv] = make_uint2((uint32_t)m, (uint32_t)(m >> 32)); \
        SYNCB;                                                                 \
    } while (0)

#define LAYERF(SRCQ, DSTQ) do {                                                \
        const uint4* xb_ = (const uint4*)(SRCQ);                               \
        uint4 s0 = xb_[0], s1 = xb_[1], s2 = xb_[2], s3 = xb_[3];              \
        int acc = bdot4(s0, s1, s2, s3, w[6][0], w[6][1], w[6][2], w[6][3]);   \
        unsigned long long m = __ballot(acc <= it6);                           \
        if (lane == 0) {                                                       \
            uint2 v_ = make_uint2((uint32_t)m, (uint32_t)(m >> 32));           \
            if (wv < 6) ((uint2*)(DSTQ))[wv] = v_;                             \
            else ((uint2*)&hx4)[wv - 6] = v_;                                  \
        }                                                                      \
        if (wv == 7 && lane < 4) ((uint32_t*)(DSTQ))[12 + lane] = embw;        \
        SYNCB;                                                                 \
    } while (0)

#define STEP(AQ, BQ, T) do {                                                   \
        /* prefetch next token's embedding early (wave 7 only) */              \
        uint32_t embw = 0;                                                     \
        if (wv == 7) embw = emb_lds[tok_lds[(T) + 1] * 4 + (lane & 3)];        \
        LAYER(0, AQ, BQ);                                                      \
        LAYER(1, BQ, AQ);                                                      \
        LAYER(2, AQ, BQ);                                                      \
        LAYER(3, BQ, AQ);                                                      \
        LAYER(4, AQ, BQ);                                                      \
        LAYER(5, BQ, AQ);                                                      \
        LAYERF(AQ, BQ);                                                        \
        uint4 hv_ = hx4;                                                       \
        if (lane < 16) {                                                       \
            int hc = __popc(hv_.x ^ h0) + __popc(hv_.y ^ h1) +                 \
                     __popc(hv_.z ^ h2) + __popc(hv_.w ^ h3);                  \
            outb[(T) * VOCABN + hvv] = (float)(RD - 2 * hc);                   \
        }                                                                      \
    } while (0)

    for (int t = 0; t < TLEN; t += 2) {
        STEP(xq0, xq1, t);
        STEP(xq1, xq0, t + 1);
    }
#undef LAYER
#undef LAYERF
#undef STEP
}

extern "C" void kernel_launch(void* const* d_in, const int* in_sizes, int n_in,
                              void* d_out, int out_size, void* d_ws, size_t ws_size,
                              hipStream_t stream) {
    const int* tokens = (const int*)d_in[0];
    const float* initial = (const float*)d_in[1];
    const float* embed = (const float*)d_in[2];
    const float* ff = (const float*)d_in[3];
    const float* ff_thresh = (const float*)d_in[4];
    const float* head = (const float*)d_in[5];
    float* out = (float*)d_out;

    uint32_t* ffp = (uint32_t*)d_ws;              // 7*16*512 = 57344 words
    uint32_t* embp = ffp + NUM_FF * 16 * DM;      // 512 words
    uint32_t* headp = embp + 512;                 // 512 words
    uint32_t* initp = headp + 512;                // 16 words
    int* ithr = (int*)(initp + 16);               // 7*512 ints

    pack_ff_kernel<<<(NUM_FF * 16 * DM + 255) / 256, 256, 0, stream>>>(ff, ffp);
    pack_thresh_kernel<<<(NUM_FF * DM + 255) / 256, 256, 0, stream>>>(ff_thresh, ithr);
    pack_small_kernel<<<1, 512, 0, stream>>>(embed, head, initial, embp, headp, initp);
    brnn_kernel<<<BATCH, 512, 0, stream>>>(tokens, ffp, ithr, embp, headp, initp, out);
}